// Round 1
// baseline (648.139 us; speedup 1.0000x reference)
//
#include <hip/hip_runtime.h>
#include <math.h>

// RayTransform: out_pos = (pos - trans) @ R ; out_dir = dir @ R
// R = I + a*K + b*K^2  (Rodrigues), shared across all rays.
// Memory-bound streaming kernel: 4 rays/thread via 3x float4 load/store.

__global__ __launch_bounds__(256) void ray_transform_kernel(
    const float* __restrict__ pos,
    const float* __restrict__ dir,
    const float* __restrict__ rot_vec,
    const float* __restrict__ trans,
    float* __restrict__ out_pos,
    float* __restrict__ out_dir,
    long long n_rays,
    int nquad)
{
    int t = blockIdx.x * blockDim.x + threadIdx.x;
    if (t >= nquad) return;

    // ---- build R (uniform across all threads; ~20 VALU ops, free) ----
    float x = rot_vec[0], y = rot_vec[1], z = rot_vec[2];
    float tx = trans[0], ty = trans[1], tz = trans[2];
    float theta2 = x * x + y * y + z * z;
    float theta = sqrtf(theta2);
    float a, b;
    if (theta < 1e-8f) {
        a = 1.0f - theta2 * (1.0f / 6.0f);
        b = 0.5f - theta2 * (1.0f / 24.0f);
    } else {
        a = sinf(theta) / theta;
        b = (1.0f - cosf(theta)) / theta2;
    }
    // K^2 terms
    float xx = x * x, yy = y * y, zz = z * z;
    float xy = x * y, xz = x * z, yz = y * z;
    // R[i][j], row i col j; out[j] = sum_i p[i]*R[i][j]
    float R00 = 1.0f - b * (yy + zz);
    float R01 = -a * z + b * xy;
    float R02 =  a * y + b * xz;
    float R10 =  a * z + b * xy;
    float R11 = 1.0f - b * (xx + zz);
    float R12 = -a * x + b * yz;
    float R20 = -a * y + b * xz;
    float R21 =  a * x + b * yz;
    float R22 = 1.0f - b * (xx + yy);

    long long ray0 = (long long)t * 4;

    if (ray0 + 4 <= n_rays) {
        // ---- vector path: 4 rays = 3 float4 per array ----
        const float4* p4 = reinterpret_cast<const float4*>(pos) + (long long)t * 3;
        const float4* d4 = reinterpret_cast<const float4*>(dir) + (long long)t * 3;
        float4 pa = p4[0], pb = p4[1], pc = p4[2];
        float4 da = d4[0], db = d4[1], dc = d4[2];

        float pin[12] = {pa.x, pa.y, pa.z, pa.w, pb.x, pb.y, pb.z, pb.w,
                         pc.x, pc.y, pc.z, pc.w};
        float din[12] = {da.x, da.y, da.z, da.w, db.x, db.y, db.z, db.w,
                         dc.x, dc.y, dc.z, dc.w};
        float po[12], doo[12];
#pragma unroll
        for (int r = 0; r < 4; ++r) {
            float px = pin[3 * r + 0] - tx;
            float py = pin[3 * r + 1] - ty;
            float pz = pin[3 * r + 2] - tz;
            po[3 * r + 0] = px * R00 + py * R10 + pz * R20;
            po[3 * r + 1] = px * R01 + py * R11 + pz * R21;
            po[3 * r + 2] = px * R02 + py * R12 + pz * R22;
            float dx = din[3 * r + 0];
            float dy = din[3 * r + 1];
            float dz = din[3 * r + 2];
            doo[3 * r + 0] = dx * R00 + dy * R10 + dz * R20;
            doo[3 * r + 1] = dx * R01 + dy * R11 + dz * R21;
            doo[3 * r + 2] = dx * R02 + dy * R12 + dz * R22;
        }

        float4* op4 = reinterpret_cast<float4*>(out_pos) + (long long)t * 3;
        float4* od4 = reinterpret_cast<float4*>(out_dir) + (long long)t * 3;
        op4[0] = make_float4(po[0], po[1], po[2], po[3]);
        op4[1] = make_float4(po[4], po[5], po[6], po[7]);
        op4[2] = make_float4(po[8], po[9], po[10], po[11]);
        od4[0] = make_float4(doo[0], doo[1], doo[2], doo[3]);
        od4[1] = make_float4(doo[4], doo[5], doo[6], doo[7]);
        od4[2] = make_float4(doo[8], doo[9], doo[10], doo[11]);
    } else {
        // ---- scalar tail (only if n_rays % 4 != 0) ----
        for (long long r = ray0; r < n_rays; ++r) {
            float px = pos[3 * r + 0] - tx;
            float py = pos[3 * r + 1] - ty;
            float pz = pos[3 * r + 2] - tz;
            out_pos[3 * r + 0] = px * R00 + py * R10 + pz * R20;
            out_pos[3 * r + 1] = px * R01 + py * R11 + pz * R21;
            out_pos[3 * r + 2] = px * R02 + py * R12 + pz * R22;
            float dx = dir[3 * r + 0];
            float dy = dir[3 * r + 1];
            float dz = dir[3 * r + 2];
            out_dir[3 * r + 0] = dx * R00 + dy * R10 + dz * R20;
            out_dir[3 * r + 1] = dx * R01 + dy * R11 + dz * R21;
            out_dir[3 * r + 2] = dx * R02 + dy * R12 + dz * R22;
        }
    }
}

extern "C" void kernel_launch(void* const* d_in, const int* in_sizes, int n_in,
                              void* d_out, int out_size, void* d_ws, size_t ws_size,
                              hipStream_t stream) {
    const float* pos     = (const float*)d_in[0];
    const float* dir     = (const float*)d_in[1];
    const float* rot_vec = (const float*)d_in[2];
    const float* trans   = (const float*)d_in[3];
    float* out = (float*)d_out;

    long long n_rays = (long long)in_sizes[0] / 3;
    float* out_pos = out;
    float* out_dir = out + (size_t)n_rays * 3;

    int nquad = (int)((n_rays + 3) / 4);
    int block = 256;
    int grid = (nquad + block - 1) / block;
    hipLaunchKernelGGL(ray_transform_kernel, dim3(grid), dim3(block), 0, stream,
                       pos, dir, rot_vec, trans, out_pos, out_dir, n_rays, nquad);
}